// Round 2
// baseline (171.866 us; speedup 1.0000x reference)
//
#include <hip/hip_runtime.h>

#define OUT_F 11008
#define IN_F  4096
#define PKW   2048   // int32 words per weight row (each word = 1 byte = 2 nibbles)
#define BLKQ  128

typedef __attribute__((ext_vector_type(8))) short          s16x8;
typedef __attribute__((ext_vector_type(8))) unsigned short u16x8;
typedef __attribute__((ext_vector_type(4))) float          f32x4;
typedef __attribute__((ext_vector_type(4))) int            i32x4;

__device__ __forceinline__ unsigned short f2bf(float f) {
    union { float f; unsigned u; } v; v.f = f;
    unsigned r = v.u + 0x8000u + ((v.u >> 16) & 1u);   // RNE
    return (unsigned short)(r >> 16);
}

// out[m][o] = bias[o]  (atomic split-K accumulates on top of this)
__global__ void init_out(const float* __restrict__ bias, float* __restrict__ out) {
    int idx = blockIdx.x * 256 + threadIdx.x;      // 64*11008 / 256 = 2752 blocks
    out[idx] = bias[idx % OUT_F];
}

// Pre-swizzle x (64x4096 f32) into MFMA A-fragment order (bf16):
//   xf[((kb*4 + mt)*64 + lane)*8 + i] = x[mt*16 + (lane&15)][kb*32 + (lane>>4)*8 + i]
__global__ void prep_xfrag(const float* __restrict__ x, unsigned short* __restrict__ xf) {
    int kb   = blockIdx.x;            // 0..127
    int t    = threadIdx.x;           // 0..255
    int mt   = t >> 6;
    int lane = t & 63;
    int m  = mt * 16 + (lane & 15);
    int k0 = kb * 32 + (lane >> 4) * 8;
    const float* xp = x + m * IN_F + k0;
    f32x4 a = *(const f32x4*)(xp);
    f32x4 b = *(const f32x4*)(xp + 4);
    u16x8 v;
    v[0] = f2bf(a[0]); v[1] = f2bf(a[1]); v[2] = f2bf(a[2]); v[3] = f2bf(a[3]);
    v[4] = f2bf(b[0]); v[5] = f2bf(b[1]); v[6] = f2bf(b[2]); v[7] = f2bf(b[3]);
    *(u16x8*)(xf + (size_t)((kb * 4 + mt) * 64 + lane) * 8) = v;
}

// Grid: 688 o-tiles x 2 K-halves = 1376 WGs of 256. Within a WG the 4 waves
// split the 2048-k half into 512-k chunks (4 rounds of 128 k each).
// Epilogue: LDS-reduce the 4 waves, then one atomicAdd per output.
__global__ __launch_bounds__(256) void qlin_main(
    const int*   __restrict__ wq,
    const float* __restrict__ scale,
    const float* __restrict__ zp,
    const unsigned short* __restrict__ xf,
    float* __restrict__ out)
{
    // 4 regions x 16 rows x 136 bf16 (pad 8) = 17408 B; reused as 16 KB f32 reduce
    __shared__ __align__(16) unsigned short smem[4 * 16 * 136];

    const int t      = threadIdx.x;
    const int oi     = blockIdx.x >> 1;
    const int kh     = blockIdx.x & 1;           // K-half
    const int o_base = oi * 16;
    const int wave   = t >> 6;
    const int lane   = t & 63;

    const int d      = t & 3;                    // j-window d*32..d*32+31
    const int row_r  = (t >> 2) & 15;
    const int region = wave;

    // per-thread dequant constants: s[j] f32, zp[j] packed as nibbles (4 regs)
    float s[32];
    unsigned zpn[4];
    {
        const float* sp  = scale + (size_t)(o_base + row_r) * BLKQ + d * 32;
        const float* zpp = zp    + (size_t)(o_base + row_r) * BLKQ + d * 32;
        #pragma unroll
        for (int g = 0; g < 4; ++g) {
            f32x4 s0 = *(const f32x4*)(sp + g * 8);
            f32x4 s1 = *(const f32x4*)(sp + g * 8 + 4);
            #pragma unroll
            for (int c = 0; c < 4; ++c) { s[g * 8 + c] = s0[c]; s[g * 8 + 4 + c] = s1[c]; }
            f32x4 z0 = *(const f32x4*)(zpp + g * 8);
            f32x4 z1 = *(const f32x4*)(zpp + g * 8 + 4);
            unsigned pk = 0;
            #pragma unroll
            for (int c = 0; c < 4; ++c) {
                pk |= ((unsigned)z0[c]) << (4 * c);
                pk |= ((unsigned)z1[c]) << (4 * (c + 4));
            }
            zpn[g] = pk;
        }
    }

    // staging base (dword index); round advances by 64 dwords (128 k)
    const int* wbase = wq + (size_t)(o_base + row_r) * PKW + kh * 1024 + region * 256 + d * 16;
    unsigned short* myw = smem + (region * 16 + row_r) * 136 + d * 32;

    f32x4 acc[4];
    #pragma unroll
    for (int mt = 0; mt < 4; ++mt) acc[mt] = (f32x4){0.f, 0.f, 0.f, 0.f};

    i32x4 wreg[4];
    #pragma unroll
    for (int q = 0; q < 4; ++q) wreg[q] = *(const i32x4*)(wbase + q * 4);

    const s16x8* xfv = (const s16x8*)xf;
    const unsigned short* bbase = smem + (wave * 16 + (lane & 15)) * 136;
    const int quad = lane >> 4;

    for (int tt = 0; tt < 4; ++tt) {
        __syncthreads();   // previous round's LDS reads complete

        // dequant 16 dwords -> 32 bf16 -> 4x16B LDS writes
        #pragma unroll
        for (int q = 0; q < 4; ++q) {
            u16x8 ob;
            #pragma unroll
            for (int pp = 0; pp < 4; ++pp) {
                unsigned dw = (unsigned)wreg[q][pp];
                int p = q * 4 + pp;                       // pair index 0..15
                unsigned zb = (zpn[p >> 2] >> ((p & 3) * 8)) & 0xFFu;
                int dh = (int)((dw >> 4) & 15u) - (int)(zb & 15u);   // k even
                int dl = (int)(dw & 15u)        - (int)(zb >> 4);    // k odd
                ob[2 * pp]     = f2bf((float)dh * s[2 * p]);
                ob[2 * pp + 1] = f2bf((float)dl * s[2 * p + 1]);
            }
            *(u16x8*)(myw + q * 8) = ob;
        }

        __syncthreads();   // tile visible

        // prefetch next round AFTER the barrier: flies during MFMA + next drain
        if (tt < 3) {
            const int* nb = wbase + (tt + 1) * 64;
            #pragma unroll
            for (int q = 0; q < 4; ++q) wreg[q] = *(const i32x4*)(nb + q * 4);
        }

        #pragma unroll
        for (int q0 = 0; q0 < 4; ++q0) {
            s16x8 bfrag = *(const s16x8*)(bbase + q0 * 32 + quad * 8);
            int kb = kh * 64 + wave * 16 + tt * 4 + q0;   // global 32-k window
            #pragma unroll
            for (int mt = 0; mt < 4; ++mt) {
                s16x8 afrag = xfv[(size_t)(kb * 4 + mt) * 64 + lane];
                acc[mt] = __builtin_amdgcn_mfma_f32_16x16x32_bf16(afrag, bfrag, acc[mt], 0, 0, 0);
            }
        }
    }

    // reduce the 4 waves via LDS, then one atomicAdd per output
    __syncthreads();
    float* lf = (float*)smem;
    {
        const int col = lane & 15;
        #pragma unroll
        for (int mt = 0; mt < 4; ++mt) {
            #pragma unroll
            for (int r = 0; r < 4; ++r) {
                int m = mt * 16 + quad * 4 + r;           // C/D: col=lane&15, row=quad*4+reg
                lf[wave * 1024 + m * 16 + col] = acc[mt][r];
            }
        }
    }
    __syncthreads();
    #pragma unroll
    for (int p = 0; p < 4; ++p) {
        int e = p * 256 + t;
        int m = e >> 4, col = e & 15;
        float v = lf[e] + lf[1024 + e] + lf[2048 + e] + lf[3072 + e];
        atomicAdd(&out[(size_t)m * OUT_F + o_base + col], v);
    }
}

extern "C" void kernel_launch(void* const* d_in, const int* in_sizes, int n_in,
                              void* d_out, int out_size, void* d_ws, size_t ws_size,
                              hipStream_t stream) {
    const float* x     = (const float*)d_in[0];
    const int*   wq    = (const int*)d_in[1];
    const float* scale = (const float*)d_in[2];
    const float* zpv   = (const float*)d_in[3];
    const float* bias  = (const float*)d_in[4];
    float* out = (float*)d_out;
    unsigned short* xf = (unsigned short*)d_ws;   // 512 KB A-fragment buffer

    init_out<<<(64 * OUT_F) / 256, 256, 0, stream>>>(bias, out);
    prep_xfrag<<<128, 256, 0, stream>>>(x, xf);
    qlin_main<<<(OUT_F / 16) * 2, 256, 0, stream>>>(wq, scale, zpv, xf, out);
}

// Round 3
// 165.844 us; speedup vs baseline: 1.0363x; 1.0363x over previous
//
#include <hip/hip_runtime.h>

#define OUT_F 11008
#define IN_F  4096
#define PKW   2048   // int32 words per weight row (each word holds 1 byte = 2 nibbles)
#define BLKQ  128

typedef __attribute__((ext_vector_type(8))) short          s16x8;
typedef __attribute__((ext_vector_type(8))) unsigned short u16x8;
typedef __attribute__((ext_vector_type(4))) float          f32x4;
typedef __attribute__((ext_vector_type(4))) int            i32x4;

__device__ __forceinline__ unsigned short f2bf(float f) {
    union { float f; unsigned u; } v; v.f = f;
    unsigned r = v.u + 0x8000u + ((v.u >> 16) & 1u);   // RNE
    return (unsigned short)(r >> 16);
}

// Pre-swizzle x (64x4096 f32) into MFMA A-fragment order (bf16):
//   xf[((kb*4 + mt)*64 + lane)*8 + i] = x[mt*16 + (lane&15)][kb*32 + (lane>>4)*8 + i]
__global__ void prep_xfrag(const float* __restrict__ x, unsigned short* __restrict__ xf) {
    int kb   = blockIdx.x;            // 0..127
    int t    = threadIdx.x;           // 0..255
    int mt   = t >> 6;
    int lane = t & 63;
    int m  = mt * 16 + (lane & 15);
    int k0 = kb * 32 + (lane >> 4) * 8;
    const float* xp = x + m * IN_F + k0;
    f32x4 a = *(const f32x4*)(xp);
    f32x4 b = *(const f32x4*)(xp + 4);
    u16x8 v;
    v[0] = f2bf(a[0]); v[1] = f2bf(a[1]); v[2] = f2bf(a[2]); v[3] = f2bf(a[3]);
    v[4] = f2bf(b[0]); v[5] = f2bf(b[1]); v[6] = f2bf(b[2]); v[7] = f2bf(b[3]);
    *(u16x8*)(xf + (size_t)((kb * 4 + mt) * 64 + lane) * 8) = v;
}

// One WG per 16-row o-tile. 4 waves split K into 1024-k quarters.
// B path is register-direct: B-fragment (n=lane&15, k=quad*8+i) == one dwordx4
// of packed weights per lane per 32-k step. No LDS, no barriers in the K loop.
__global__ __launch_bounds__(256) void qlin_main(
    const int*   __restrict__ wq,
    const float* __restrict__ scale,
    const float* __restrict__ zp,
    const float* __restrict__ bias,
    const unsigned short* __restrict__ xf,
    float* __restrict__ out)
{
    __shared__ __align__(16) float lf[4096];     // 16 KB: epilogue reduce only

    const int t      = threadIdx.x;
    const int o_base = blockIdx.x * 16;
    const int wave   = t >> 6;                   // K-quarter
    const int lane   = t & 63;
    const int col16  = lane & 15;                // n (output row of W)
    const int quad   = lane >> 4;                // k-slice within 32-k window
    const int row    = o_base + col16;

    // per-lane dequant constants for its weight row:
    //   j = k % 128 = p*32 + quad*8 + e   (p = kb % 4)
    float s[32];
    unsigned zpn[4];
    {
        const float* sp  = scale + (size_t)row * BLKQ;
        const float* zpp = zp    + (size_t)row * BLKQ;
        #pragma unroll
        for (int p = 0; p < 4; ++p) {
            int off = p * 32 + quad * 8;
            f32x4 s0 = *(const f32x4*)(sp + off);
            f32x4 s1 = *(const f32x4*)(sp + off + 4);
            f32x4 z0 = *(const f32x4*)(zpp + off);
            f32x4 z1 = *(const f32x4*)(zpp + off + 4);
            unsigned pk = 0;
            #pragma unroll
            for (int c = 0; c < 4; ++c) {
                s[p * 8 + c]     = s0[c];
                s[p * 8 + 4 + c] = s1[c];
                pk |= ((unsigned)z0[c]) << (4 * c);
                pk |= ((unsigned)z1[c]) << (4 * (c + 4));
            }
            zpn[p] = pk;
        }
    }

    // weight pointer: dword index = row*2048 + (wave*32 + kb)*16 + quad*4
    const int* wp = wq + (size_t)row * PKW + wave * 512 + quad * 4;
    const s16x8* xfv = (const s16x8*)xf;
    const int kgb = wave * 32;                   // this wave's global kb base

    f32x4 acc[4];
    #pragma unroll
    for (int mt = 0; mt < 4; ++mt) acc[mt] = (f32x4){0.f, 0.f, 0.f, 0.f};

    // prefetch: weights depth 4, afrags depth 2
    i32x4 wr[4];
    #pragma unroll
    for (int p = 0; p < 4; ++p) wr[p] = *(const i32x4*)(wp + p * 16);

    s16x8 ar[2][4];
    #pragma unroll
    for (int sl = 0; sl < 2; ++sl)
        #pragma unroll
        for (int mt = 0; mt < 4; ++mt)
            ar[sl][mt] = xfv[(size_t)(((kgb + sl) * 4 + mt) * 64 + lane)];

    for (int kb4 = 0; kb4 < 8; ++kb4) {
        #pragma unroll
        for (int p = 0; p < 4; ++p) {
            const int kb = kb4 * 4 + p;

            // issue next weight load early (depth 4)
            int kn = kb + 4; if (kn > 31) kn = 31;
            i32x4 wnext = *(const i32x4*)(wp + kn * 16);

            // dequant wr[p] -> bf16 B fragment (8 elems: k = quad*8 + e)
            u16x8 ub;
            #pragma unroll
            for (int e = 0; e < 8; ++e) {
                unsigned dw = (unsigned)wr[p][e >> 1];
                int wi = (e & 1) ? (int)(dw & 15u) : (int)((dw >> 4) & 15u);
                int zi = (int)((zpn[p] >> (4 * e)) & 15u);
                ub[e] = f2bf((float)(wi - zi) * s[p * 8 + e]);
            }
            s16x8 bfrag;
            #pragma unroll
            for (int e = 0; e < 8; ++e) bfrag[e] = (short)ub[e];

            #pragma unroll
            for (int mt = 0; mt < 4; ++mt)
                acc[mt] = __builtin_amdgcn_mfma_f32_16x16x32_bf16(ar[p & 1][mt], bfrag, acc[mt], 0, 0, 0);

            // refill afrag slot for kb+2 (depth 2)
            int ka = kb + 2; if (ka > 31) ka = 31;
            #pragma unroll
            for (int mt = 0; mt < 4; ++mt)
                ar[p & 1][mt] = xfv[(size_t)(((kgb + ka) * 4 + mt) * 64 + lane)];

            wr[p] = wnext;
        }
    }

    // reduce 4 K-quarter waves via LDS, add bias, store
    #pragma unroll
    for (int mt = 0; mt < 4; ++mt) {
        #pragma unroll
        for (int r = 0; r < 4; ++r) {
            int m = mt * 16 + quad * 4 + r;      // C/D: col=lane&15, row=quad*4+reg
            lf[wave * 1024 + m * 16 + col16] = acc[mt][r];
        }
    }
    __syncthreads();
    #pragma unroll
    for (int p = 0; p < 4; ++p) {
        int e = p * 256 + t;
        int m = e >> 4, col = e & 15;
        float v = lf[e] + lf[1024 + e] + lf[2048 + e] + lf[3072 + e] + bias[o_base + col];
        out[(size_t)m * OUT_F + o_base + col] = v;
    }
}

extern "C" void kernel_launch(void* const* d_in, const int* in_sizes, int n_in,
                              void* d_out, int out_size, void* d_ws, size_t ws_size,
                              hipStream_t stream) {
    const float* x     = (const float*)d_in[0];
    const int*   wq    = (const int*)d_in[1];
    const float* scale = (const float*)d_in[2];
    const float* zpv   = (const float*)d_in[3];
    const float* bias  = (const float*)d_in[4];
    float* out = (float*)d_out;
    unsigned short* xf = (unsigned short*)d_ws;   // 512 KB A-fragment buffer

    prep_xfrag<<<128, 256, 0, stream>>>(x, xf);
    qlin_main<<<OUT_F / 16, 256, 0, stream>>>(wq, scale, zpv, bias, xf, out);
}